// Round 11
// baseline (21.991 us; speedup 1.0000x reference)
//
#include <hip/hip_runtime.h>

typedef __fp16 h2 __attribute__((ext_vector_type(2)));
#define HALF_INV2PI 0.07957747154594766788f

// ---------------------------------------------------------------------------
// Packed f16 helpers (forms verified on gfx950, rounds 4-10).
// ---------------------------------------------------------------------------
__device__ __forceinline__ h2 hpk(float lo, float hi) {
  return __builtin_amdgcn_cvt_pkrtz(lo, hi);
}
__device__ __forceinline__ h2 hsp(float a) {
  return __builtin_amdgcn_cvt_pkrtz(a, a);
}
__device__ __forceinline__ h2 hmul(h2 a, h2 b) {
  h2 d; asm("v_pk_mul_f16 %0, %1, %2" : "=v"(d) : "v"(a), "v"(b)); return d;
}
__device__ __forceinline__ h2 hfma(h2 a, h2 b, h2 c) {
  h2 d; asm("v_pk_fma_f16 %0, %1, %2, %3" : "=v"(d) : "v"(a), "v"(b), "v"(c));
  return d;
}
__device__ __forceinline__ h2 hfms(h2 a, h2 b, h2 c) {  // a*b - c
  h2 d; asm("v_pk_fma_f16 %0, %1, %2, %3 neg_lo:[0,0,1] neg_hi:[0,0,1]"
            : "=v"(d) : "v"(a), "v"(b), "v"(c));
  return d;
}
__device__ __forceinline__ h2 hfma_sw(h2 a, h2 b, h2 c) {  // a*swap(b) + c
  h2 d; asm("v_pk_fma_f16 %0, %1, %2, %3 op_sel:[0,1,0] op_sel_hi:[1,0,1]"
            : "=v"(d) : "v"(a), "v"(b), "v"(c));
  return d;
}
template<int CTRL>
__device__ __forceinline__ h2 hdpp(h2 v) {
  int x = __builtin_amdgcn_mov_dpp(__builtin_bit_cast(int, v), CTRL, 0xf, 0xf, true);
  return __builtin_bit_cast(h2, x);
}
template<int OFF>
__device__ __forceinline__ h2 hswz(h2 v) {
  int x = __builtin_amdgcn_ds_swizzle(__builtin_bit_cast(int, v), OFF);
  return __builtin_bit_cast(h2, x);
}
__device__ __forceinline__ float hdot2(h2 a, h2 b, float c) {
#if __has_builtin(__builtin_amdgcn_fdot2)
  return __builtin_amdgcn_fdot2(a, b, c, false);
#else
  return __builtin_fmaf((float)a.y, (float)b.y,
         __builtin_fmaf((float)a.x, (float)b.x, c));
#endif
}

__device__ __forceinline__ void hw_sc(float rev, float& s, float& c) {
  s = __builtin_amdgcn_sinf(rev);
  c = __builtin_amdgcn_cosf(rev);
}

template<int J>
__device__ __forceinline__ float rl(float x) {
  return __int_as_float(__builtin_amdgcn_readlane(__float_as_int(x), J));
}
struct PC { float cB,sB,cA,sA,c0,s0,cd,sd,c4,s4; };
template<int J>
__device__ __forceinline__ PC loadpc(float cB,float sB,float cA,float sA,
                                     float c0,float s0,float cd,float sd,
                                     float c4,float s4) {
  PC c;
  c.cB=rl<J>(cB); c.sB=rl<J>(sB); c.cA=rl<J>(cA); c.sA=rl<J>(sA);
  c.c0=rl<J>(c0); c.s0=rl<J>(s0); c.cd=rl<J>(cd); c.sd=rl<J>(sd);
  c.c4=rl<J>(c4); c.s4=rl<J>(s4);
  return c;
}

// complex phase multiply on set s: R+iI *= (zr + i*zi), per-q1-component
#define CDIAG(s, zr, zi) do { \
    h2 _t  = hmul((zi), I[s]); \
    h2 _nR = hfms((zr), R[s], _t); \
    I[s] = hfma((zi), R[s], hmul((zr), I[s])); \
    R[s] = _nR; } while (0)

// ---------------------------------------------------------------------------
// Layout: 4 samples/wave (sample bits = lane{5,2}) -> grid 2048 blocks =
//   8 blocks/CU = 32 waves/CU = 8 waves/SIMD (grid-occupancy fix vs r10).
// Per-lane 16 complex amps in f16: set s = q0*4 + q2*2 + q7 (R[s],I[s] = h2),
//   halves = q1.  Lane qubit bits: q4=bit4 (xor16 ds_swizzle, 1 stage),
//   q3=bit3 (DPP row_ror:8, 2 stages), q6=bit1, q5=bit0 (quad_perm).
// ---------------------------------------------------------------------------
__global__ __launch_bounds__(256, 8) void qnn_main(const float* __restrict__ in,
                                                   const float* __restrict__ w,
                                                   float* __restrict__ out) {
  const int tid = threadIdx.x;
  const int wid = tid >> 6;
  const int lane = tid & 63;
  const int wv = blockIdx.x * 4 + wid;
  const int q4 = (lane >> 4) & 1, q3 = (lane >> 3) & 1,
            q6 = (lane >> 1) & 1, q5 = lane & 1;
  const int smp = ((lane >> 5) & 1) * 2 + ((lane >> 2) & 1);
  const float sgn3 = q3 ? 1.f : -1.f;
  const float sgn4 = q4 ? 1.f : -1.f;
  const float sgn5 = q5 ? 1.f : -1.f;
  const float sgn6 = q6 ? 1.f : -1.f;

  // ---- in-kernel prep: lane j (j<9) computes pair j's 10 gate constants
  float gcB,gsB,gcA,gsA,gc0,gs0,gcd,gsd,gc4,gs4;
  {
    const int jj = (lane < 9) ? lane : 0;
    const float* wp = w + jj * 5;
    float w0 = wp[0], w1 = wp[1], w2 = wp[2], w3 = wp[3], w4 = wp[4];
    hw_sc(w0 * HALF_INV2PI, gsB, gcB);
    hw_sc((w0 + w1) * HALF_INV2PI, gsA, gcA);
    hw_sc((w2 + w3) * HALF_INV2PI, gs0, gc0);
    hw_sc((w2 - w3) * HALF_INV2PI, gsd, gcd);
    hw_sc(w4 * HALF_INV2PI, gs4, gc4);
  }
#define LOADPC(J) loadpc<J>(gcB,gsB,gcA,gsA,gc0,gs0,gcd,gsd,gc4,gs4)

  // ---- embedding: product state (real). b[8] spans sets {q0,q2,q7};
  // lane factors q3,q4,q5,q6 folded into prodL; q1 -> components.
  float b[8];
  h2 vq1p, mq1p;
  {
    const float* ip = in + (wv * 4 + smp) * 8;
    float4 A4 = ((const float4*)ip)[0], B4 = ((const float4*)ip)[1];
    float xs[8] = {A4.x, A4.y, A4.z, A4.w, B4.x, B4.y, B4.z, B4.w};
    float vc[8], vs[8];
#pragma unroll
    for (int q = 0; q < 8; ++q)
      hw_sc(__builtin_fmaf(xs[q], HALF_INV2PI, 0.125f), vs[q], vc[q]);
    float prodL = (q3 ? vs[3] : vc[3]) * (q4 ? vs[4] : vc[4]);
    prodL *= (q5 ? vs[5] : vc[5]) * (q6 ? vs[6] : vc[6]);
    float t0 = prodL * vc[0], t1 = prodL * vs[0];
    float u[4] = {t0 * vc[2], t0 * vs[2], t1 * vc[2], t1 * vs[2]};  // q0*2+q2
#pragma unroll
    for (int i = 0; i < 4; ++i) { b[i*2] = u[i]*vc[7]; b[i*2+1] = u[i]*vs[7]; }
    vq1p = hpk(vc[1], vs[1]);
    mq1p = hpk(-vc[1], vs[1]);
  }

  h2 R[8], I[8];

  // ---- G0 = D1_0(c=q0,t=q1) on real state;  B0: target q1 (op_sel swap)
  PC P0 = LOADPC(0);
  {
    h2 Y0 = hpk(-P0.s0, P0.s0);
    h2 X1 = hpk(P0.sd, -P0.sd);
    h2 c0v = hsp(P0.c0), cdv = hsp(P0.cd);
#pragma unroll
    for (int s = 0; s < 8; ++s) {
      const bool Q0 = (s & 4) != 0;
      float br = b[s] * (Q0 ? P0.cA : P0.cB);
      float bi = b[s] * (Q0 ? P0.sA : P0.sB);
      h2 r = hmul(hsp(br), vq1p);
      h2 i = hmul(hsp(bi), mq1p);
      if (!Q0) {
        R[s] = hfma_sw(Y0, r, hmul(c0v, r));
        I[s] = hfma_sw(Y0, i, hmul(c0v, i));
      } else {
        R[s] = hfma_sw(cdv, r, hmul(X1, r));
        I[s] = hfma_sw(cdv, i, hmul(X1, i));
      }
    }
  }

  // ---- G1 = D3_0(c=q0,t=q1) * D1_1(c=q1,t=q2)
  PC P1 = LOADPC(1);
  {
    h2 zr1p = hpk(P1.cB, P1.cA);
    h2 zi1p[2] = { hpk(-P1.sB, -P1.sA), hpk(P1.sB, P1.sA) };  // by q2
    h2 zrBp[2], ziBp[2];
#pragma unroll
    for (int t = 0; t < 2; ++t) {
      float eps = t ? 1.f : -1.f;
      float zix = eps * P1.sB, ziy = eps * P1.sA;
      float zrx = __builtin_fmaf(P0.s4, zix, P0.c4 * P1.cB);
      float zry = __builtin_fmaf(-P0.s4, ziy, P0.c4 * P1.cA);
      float zibx = __builtin_fmaf(-P0.s4, P1.cB, P0.c4 * zix);
      float ziby = __builtin_fmaf(P0.s4, P1.cA, P0.c4 * ziy);
      zrBp[t] = hpk(zrx, zry); ziBp[t] = hpk(zibx, ziby);
    }
#pragma unroll
    for (int s = 0; s < 8; ++s) {
      const int Q2 = (s >> 1) & 1;
      if (s & 4) { CDIAG(s, zrBp[Q2], ziBp[Q2]); }
      else       { CDIAG(s, zr1p, zi1p[Q2]); }
    }
  }
  // ---- B1: target q2 (register mix s<->s|2), control q1 (component vector)
  {
    h2 m00 = hpk(P1.c0, P1.sd), m01 = hpk(-P1.s0, P1.cd);
    h2 m10 = hpk(P1.s0, P1.cd), m11 = hpk(P1.c0, -P1.sd);
#pragma unroll
    for (int s = 0; s < 8; ++s) {
      if (s & 2) continue;
      const int a = s, c = s | 2;
      h2 t;
      t    = hfma(m01, R[c], hmul(m00, R[a]));
      R[c] = hfma(m11, R[c], hmul(m10, R[a])); R[a] = t;
      t    = hfma(m01, I[c], hmul(m00, I[a]));
      I[c] = hfma(m11, I[c], hmul(m10, I[a])); I[a] = t;
    }
  }

  // ---- G2 = D3_1(c=q1,t=q2) * D1_2(c=q2,t=q3)
  PC P2 = LOADPC(2);
  {
    float wr0 = P2.cB, wi0 = sgn3 * P2.sB;
    float wr1 = P2.cA, wi1 = sgn3 * P2.sA;
    h2 zrq[2] = { hpk(wr0, __builtin_fmaf(P1.s4, wi0, P1.c4*wr0)),
                  hpk(wr1, __builtin_fmaf(-P1.s4, wi1, P1.c4*wr1)) };
    h2 ziq[2] = { hpk(wi0, __builtin_fmaf(P1.c4, wi0, -P1.s4*wr0)),
                  hpk(wi1, __builtin_fmaf(P1.c4, wi1,  P1.s4*wr1)) };
#pragma unroll
    for (int s = 0; s < 8; ++s) {
      const int Q2 = (s >> 1) & 1;
      CDIAG(s, zrq[Q2], ziq[Q2]);
    }
  }
  // ---- B2: target q3 (DPP ror8), control q2 (set bit1)
  {
    float Y0 = q3 ? P2.s0 : -P2.s0;
    float X1 = q3 ? -P2.sd : P2.sd;
    h2 Xv[2] = { hsp(P2.c0), hsp(X1) };
    h2 Yv[2] = { hsp(Y0), hsp(P2.cd) };
#pragma unroll
    for (int s = 0; s < 8; ++s) {
      const int Q2 = (s >> 1) & 1;
      h2 o = hdpp<0x128>(R[s]); R[s] = hfma(Yv[Q2], o, hmul(Xv[Q2], R[s]));
      o = hdpp<0x128>(I[s]);    I[s] = hfma(Yv[Q2], o, hmul(Xv[Q2], I[s]));
    }
  }

  // ---- G3 = D3_2(c=q2,t=q3) * D1_3(c=q3,t=q0)
  PC P3 = LOADPC(3);
  {
    float dr = q3 ? P3.cA : P3.cB;
    float di = q3 ? P3.sA : P3.sB;
    float ui = sgn3 * P2.s4;
    h2 z3r[2][2], z3i[2][2];  // [q2][q0]
    z3r[0][0] = hsp(dr);  z3i[0][0] = hsp(-di);
    z3r[0][1] = hsp(dr);  z3i[0][1] = hsp(di);
    z3r[1][0] = hsp(__builtin_fmaf(ui, di, P2.c4*dr));
    z3i[1][0] = hsp(__builtin_fmaf(ui, dr, -P2.c4*di));
    z3r[1][1] = hsp(__builtin_fmaf(-ui, di, P2.c4*dr));
    z3i[1][1] = hsp(__builtin_fmaf(ui, dr,  P2.c4*di));
#pragma unroll
    for (int s = 0; s < 8; ++s) {
      const int Q2 = (s >> 1) & 1, Q0 = (s >> 2) & 1;
      CDIAG(s, z3r[Q2][Q0], z3i[Q2][Q0]);
    }
  }
  // ---- B3: target q0 (register mix s<->s|4), control q3 (lane)
  {
    float m00 = q3 ? P3.sd : P3.c0, m01 = q3 ? P3.cd : -P3.s0;
    float m10 = q3 ? P3.cd : P3.s0, m11 = q3 ? -P3.sd : P3.c0;
    h2 M00 = hsp(m00), M01 = hsp(m01), M10 = hsp(m10), M11 = hsp(m11);
#pragma unroll
    for (int s = 0; s < 4; ++s) {
      const int a = s, c = s | 4;
      h2 t;
      t    = hfma(M01, R[c], hmul(M00, R[a]));
      R[c] = hfma(M11, R[c], hmul(M10, R[a])); R[a] = t;
      t    = hfma(M01, I[c], hmul(M00, I[a]));
      I[c] = hfma(M11, I[c], hmul(M10, I[a])); I[a] = t;
    }
  }

  // ---- G4 = D3_3(c=q3,t=q0) * D1_4(c=q3,t=q4)   (q4 now lane-uniform)
  PC P4 = LOADPC(4);
  {
    float ar = q3 ? P3.c4 : 1.f, ai = q3 ? P3.s4 : 0.f;
    float wr = q3 ? P4.cA : P4.cB;
    float wi4 = sgn4 * (q3 ? P4.sA : P4.sB);
    float p = ar * wr, t_ = ai * wr, r4 = ar * wi4, qq = ai * wi4;
    h2 zr_[2] = { hsp(p + qq), hsp(p - qq) };     // [q0]
    h2 zi_[2] = { hsp(r4 - t_), hsp(r4 + t_) };
#pragma unroll
    for (int s = 0; s < 8; ++s) {
      const int Q0 = (s >> 2) & 1;
      CDIAG(s, zr_[Q0], zi_[Q0]);
    }
  }
  // ---- B4: target q4 (xor16 via ds_swizzle), control q3 (lane)
  {
    float X = q3 ? (q4 ? -P4.sd : P4.sd) : P4.c0;
    float Y = q3 ? P4.cd : (q4 ? P4.s0 : -P4.s0);
    h2 Xv = hsp(X), Yv = hsp(Y);
#pragma unroll
    for (int s = 0; s < 8; ++s) {
      h2 o = hswz<0x401F>(R[s]); R[s] = hfma(Yv, o, hmul(Xv, R[s]));
      o = hswz<0x401F>(I[s]);    I[s] = hfma(Yv, o, hmul(Xv, I[s]));
    }
  }

  // ---- G5 = D3_4(c=q3,t=q4) * D1_5(c=q4,t=q5)   (all lane-uniform)
  PC P5 = LOADPC(5);
  {
    float ur = q3 ? P4.c4 : 1.f;
    float ui4 = q3 ? sgn4 * P4.s4 : 0.f;
    float wr = q4 ? P5.cA : P5.cB;
    float wi = sgn5 * (q4 ? P5.sA : P5.sB);
    h2 zr = hsp(__builtin_fmaf(-ui4, wi, ur * wr));
    h2 zi = hsp(__builtin_fmaf(ui4, wr, ur * wi));
#pragma unroll
    for (int s = 0; s < 8; ++s) CDIAG(s, zr, zi);
  }
  // ---- B5: target q5 (DPP quad_perm [1,0,3,2]), control q4 (lane)
  {
    float X = q4 ? (q5 ? -P5.sd : P5.sd) : P5.c0;
    float Y = q4 ? P5.cd : (q5 ? P5.s0 : -P5.s0);
    h2 Xv = hsp(X), Yv = hsp(Y);
#pragma unroll
    for (int s = 0; s < 8; ++s) {
      h2 o = hdpp<0xB1>(R[s]); R[s] = hfma(Yv, o, hmul(Xv, R[s]));
      o = hdpp<0xB1>(I[s]);    I[s] = hfma(Yv, o, hmul(Xv, I[s]));
    }
  }

  // ---- G6 = D3_5(c=q4,t=q5) * D1_6(c=q5,t=q6)   (all lane-uniform)
  PC P6 = LOADPC(6);
  {
    float ur6 = q4 ? P5.c4 : 1.f;
    float vi6 = q4 ? sgn5 * P5.s4 : 0.f;
    float wr = q5 ? P6.cA : P6.cB;
    float wi = sgn6 * (q5 ? P6.sA : P6.sB);
    h2 zr = hsp(__builtin_fmaf(-vi6, wi, ur6 * wr));
    h2 zi = hsp(__builtin_fmaf(vi6, wr, ur6 * wi));
#pragma unroll
    for (int s = 0; s < 8; ++s) CDIAG(s, zr, zi);
  }
  // ---- B6: target q6 (DPP quad_perm [2,3,0,1]), control q5 (lane)
  {
    float X = q5 ? (q6 ? -P6.sd : P6.sd) : P6.c0;
    float Y = q5 ? P6.cd : (q6 ? P6.s0 : -P6.s0);
    h2 Xv = hsp(X), Yv = hsp(Y);
#pragma unroll
    for (int s = 0; s < 8; ++s) {
      h2 o = hdpp<0x4E>(R[s]); R[s] = hfma(Yv, o, hmul(Xv, R[s]));
      o = hdpp<0x4E>(I[s]);    I[s] = hfma(Yv, o, hmul(Xv, I[s]));
    }
  }

  // ---- G7 = D3_6(c=q5,t=q6) * D1_7(c=q6,t=q7)   (q7 = set bit0)
  PC P7 = LOADPC(7);
  {
    float ur = q5 ? P6.c4 : 1.f;
    float vi = sgn6 * (q5 ? P6.s4 : 0.f);
    float wr = q6 ? P7.cA : P7.cB, wi = q6 ? P7.sA : P7.sB;
    h2 z7r[2] = { hsp(__builtin_fmaf(vi, wi, ur*wr)),
                  hsp(__builtin_fmaf(-vi, wi, ur*wr)) };
    h2 z7i[2] = { hsp(__builtin_fmaf(vi, wr, -ur*wi)),
                  hsp(__builtin_fmaf(vi, wr, ur*wi)) };
#pragma unroll
    for (int s = 0; s < 8; ++s) {
      const int Q7 = s & 1;
      CDIAG(s, z7r[Q7], z7i[Q7]);
    }
  }
  // ---- B7: target q7 (register mix s<->s|1), control q6 (lane)
  {
    float m00 = q6 ? P7.sd : P7.c0, m01 = q6 ? P7.cd : -P7.s0;
    float m10 = q6 ? P7.cd : P7.s0, m11 = q6 ? -P7.sd : P7.c0;
    h2 M00 = hsp(m00), M01 = hsp(m01), M10 = hsp(m10), M11 = hsp(m11);
#pragma unroll
    for (int s = 0; s < 8; ++s) {
      if (s & 1) continue;
      const int a = s, c = s | 1;
      h2 t;
      t    = hfma(M01, R[c], hmul(M00, R[a]));
      R[c] = hfma(M11, R[c], hmul(M10, R[a])); R[a] = t;
      t    = hfma(M01, I[c], hmul(M00, I[a]));
      I[c] = hfma(M11, I[c], hmul(M10, I[a])); I[a] = t;
    }
  }

  // ---- G8 = D3_7(c=q6,t=q7) * D1_8(c=q7,t=q3)
  PC P8 = LOADPC(8);
  {
    float ur = q6 ? P7.c4 : 1.f, ui = q6 ? P7.s4 : 0.f;
    float w0r = P8.cB, w0i = sgn3 * P8.sB;
    float w1r = P8.cA, w1i = sgn3 * P8.sA;
    h2 z8r[2] = { hsp(__builtin_fmaf(ui, w0i, ur*w0r)),
                  hsp(__builtin_fmaf(-ui, w1i, ur*w1r)) };
    h2 z8i[2] = { hsp(__builtin_fmaf(-ui, w0r, ur*w0i)),
                  hsp(__builtin_fmaf(ui, w1r, ur*w1i)) };
#pragma unroll
    for (int s = 0; s < 8; ++s) {
      const int Q7 = s & 1;
      CDIAG(s, z8r[Q7], z8i[Q7]);
    }
  }
  // ---- B8: target q3 (DPP ror8), control q7 (set bit0). Final D3 dropped.
  {
    float Y0 = q3 ? P8.s0 : -P8.s0;
    float X1 = q3 ? -P8.sd : P8.sd;
    h2 Xv[2] = { hsp(P8.c0), hsp(X1) };
    h2 Yv[2] = { hsp(Y0), hsp(P8.cd) };
#pragma unroll
    for (int s = 0; s < 8; ++s) {
      const int Q7 = s & 1;
      h2 o = hdpp<0x128>(R[s]); R[s] = hfma(Yv[Q7], o, hmul(Xv[Q7], R[s]));
      o = hdpp<0x128>(I[s]);    I[s] = hfma(Yv[Q7], o, hmul(Xv[Q7], I[s]));
    }
  }

  // ---- probs: marginalize q0,q2 (set bits), q1 (dot2), f32 accumulate
  float acc[2] = {0.f, 0.f};
#pragma unroll
  for (int s = 0; s < 8; ++s) {
    acc[s & 1] = hdot2(R[s], R[s], acc[s & 1]);
    acc[s & 1] = hdot2(I[s], I[s], acc[s & 1]);
  }
  // out index k = q3*16 + q4*8 + q5*4 + q6*2 + q7 ; acc[j]: j = q7
  const int k0 = q3 * 16 + q4 * 8 + q5 * 4 + q6 * 2;
  float* ob = out + (wv * 4 + smp) * 32 + k0;
  *(float2*)ob = make_float2(acc[0], acc[1]);
}

extern "C" void kernel_launch(void* const* d_in, const int* in_sizes, int n_in,
                              void* d_out, int out_size, void* d_ws, size_t ws_size,
                              hipStream_t stream) {
  const float* inputs = (const float*)d_in[0];   // (B, 8) f32
  const float* weights = (const float*)d_in[1];  // (1, 45) f32
  float* out = (float*)d_out;                    // (B, 32) f32
  const int B = in_sizes[0] / 8;

  hipLaunchKernelGGL(qnn_main, dim3(B / 16), dim3(256), 0, stream,
                     inputs, weights, out);
}

// Round 12
// 19.442 us; speedup vs baseline: 1.1312x; 1.1312x over previous
//
#include <hip/hip_runtime.h>

typedef __fp16 h2 __attribute__((ext_vector_type(2)));
#define HALF_INV2PI 0.07957747154594766788f

// ---------------------------------------------------------------------------
// Packed f16 helpers. VOP3P f16 is FULL-rate (2 f16 FMA/lane/2cyc) vs
// half-rate pk_f32. op_sel/neg encodings identical to the verified f32 forms.
// Coefficients are computed per-lane in f32 and packed via v_cvt_pkrtz.
// ---------------------------------------------------------------------------
__device__ __forceinline__ h2 hpk(float lo, float hi) {
  return __builtin_amdgcn_cvt_pkrtz(lo, hi);
}
__device__ __forceinline__ h2 hsp(float a) {
  return __builtin_amdgcn_cvt_pkrtz(a, a);
}
__device__ __forceinline__ h2 hmul(h2 a, h2 b) {
  h2 d; asm("v_pk_mul_f16 %0, %1, %2" : "=v"(d) : "v"(a), "v"(b)); return d;
}
__device__ __forceinline__ h2 hfma(h2 a, h2 b, h2 c) {
  h2 d; asm("v_pk_fma_f16 %0, %1, %2, %3" : "=v"(d) : "v"(a), "v"(b), "v"(c));
  return d;
}
__device__ __forceinline__ h2 hfms(h2 a, h2 b, h2 c) {  // a*b - c
  h2 d; asm("v_pk_fma_f16 %0, %1, %2, %3 neg_lo:[0,0,1] neg_hi:[0,0,1]"
            : "=v"(d) : "v"(a), "v"(b), "v"(c));
  return d;
}
__device__ __forceinline__ h2 hfma_sw(h2 a, h2 b, h2 c) {  // a*swap(b) + c
  h2 d; asm("v_pk_fma_f16 %0, %1, %2, %3 op_sel:[0,1,0] op_sel_hi:[1,0,1]"
            : "=v"(d) : "v"(a), "v"(b), "v"(c));
  return d;
}
template<int CTRL>
__device__ __forceinline__ h2 hdpp(h2 v) {
  int x = __builtin_amdgcn_mov_dpp(__builtin_bit_cast(int, v), CTRL, 0xf, 0xf, true);
  return __builtin_bit_cast(h2, x);
}
__device__ __forceinline__ float hdot2(h2 a, h2 b, float c) {
#if __has_builtin(__builtin_amdgcn_fdot2)
  return __builtin_amdgcn_fdot2(a, b, c, false);
#else
  return __builtin_fmaf((float)a.y, (float)b.y,
         __builtin_fmaf((float)a.x, (float)b.x, c));
#endif
}

__device__ __forceinline__ void hw_sc(float rev, float& s, float& c) {
  s = __builtin_amdgcn_sinf(rev);
  c = __builtin_amdgcn_cosf(rev);
}

template<int J>
__device__ __forceinline__ float rl(float x) {
  return __int_as_float(__builtin_amdgcn_readlane(__float_as_int(x), J));
}
struct PC { float cB,sB,cA,sA,c0,s0,cd,sd,c4,s4; };
template<int J>
__device__ __forceinline__ PC loadpc(float cB,float sB,float cA,float sA,
                                     float c0,float s0,float cd,float sd,
                                     float c4,float s4) {
  PC c;
  c.cB=rl<J>(cB); c.sB=rl<J>(sB); c.cA=rl<J>(cA); c.sA=rl<J>(sA);
  c.c0=rl<J>(c0); c.s0=rl<J>(s0); c.cd=rl<J>(cd); c.sd=rl<J>(sd);
  c.c4=rl<J>(c4); c.s4=rl<J>(s4);
  return c;
}

// complex phase multiply on set s: R+iI *= (zr + i*zi), per-q1-component
#define CDIAG(s, zr, zi) do { \
    h2 _t  = hmul((zi), I[s]); \
    h2 _nR = hfms((zr), R[s], _t); \
    I[s] = hfma((zi), R[s], hmul((zr), I[s])); \
    R[s] = _nR; } while (0)

// ---------------------------------------------------------------------------
// Layout: 8 samples/wave (sample bits = lane{5,4,2}); per-lane 32 complex amps
//   in f16: set s = q0*8 + q2*4 + q4*2 + q7 (R[s],I[s] = h2), halves = q1.
//   Lane qubit bits: q3=bit3 (DPP row_ror:8), q6=bit1 (quad_perm [2,3,0,1]),
//   q5=bit0 (quad_perm [1,0,3,2]). Zero LDS/DS ops.
// Best-measured configuration (R9: 19.36 us). Fixed-floor model: time ~
// 11.6us overhead + 1.14us/M-instr; this structure sits at that floor.
// ---------------------------------------------------------------------------
__global__ __launch_bounds__(256, 4) void qnn_main(const float* __restrict__ in,
                                                   const float* __restrict__ w,
                                                   float* __restrict__ out) {
  const int tid = threadIdx.x;
  const int wid = tid >> 6;
  const int lane = tid & 63;
  const int wv = blockIdx.x * 4 + wid;
  const int q3 = (lane >> 3) & 1, q6 = (lane >> 1) & 1, q5 = lane & 1;
  const int smp = ((lane >> 5) & 1) * 4 + ((lane >> 4) & 1) * 2 + ((lane >> 2) & 1);
  const float sgn3 = q3 ? 1.f : -1.f;
  const float sgn5 = q5 ? 1.f : -1.f;
  const float sgn6 = q6 ? 1.f : -1.f;

  // ---- in-kernel prep: lane j (j<9) computes pair j's 10 gate constants
  float gcB,gsB,gcA,gsA,gc0,gs0,gcd,gsd,gc4,gs4;
  {
    const int jj = (lane < 9) ? lane : 0;
    const float* wp = w + jj * 5;
    float w0 = wp[0], w1 = wp[1], w2 = wp[2], w3 = wp[3], w4 = wp[4];
    hw_sc(w0 * HALF_INV2PI, gsB, gcB);
    hw_sc((w0 + w1) * HALF_INV2PI, gsA, gcA);
    hw_sc((w2 + w3) * HALF_INV2PI, gs0, gc0);
    hw_sc((w2 - w3) * HALF_INV2PI, gsd, gcd);
    hw_sc(w4 * HALF_INV2PI, gs4, gc4);
  }
#define LOADPC(J) loadpc<J>(gcB,gsB,gcA,gsA,gc0,gs0,gcd,gsd,gc4,gs4)

  // ---- embedding: this lane's sample; product state, all real (f32)
  const float* ip = in + (wv * 8 + smp) * 8;
  float4 A4 = ((const float4*)ip)[0], B4 = ((const float4*)ip)[1];
  float xs[8] = {A4.x, A4.y, A4.z, A4.w, B4.x, B4.y, B4.z, B4.w};
  float vc[8], vs[8];
#pragma unroll
  for (int q = 0; q < 8; ++q)
    hw_sc(__builtin_fmaf(xs[q], HALF_INV2PI, 0.125f), vs[q], vc[q]);
  float prodL = (q3 ? vs[3] : vc[3]) * (q5 ? vs[5] : vc[5]) * (q6 ? vs[6] : vc[6]);
  float b[16];
  {
    float t0 = prodL * vc[0], t1 = prodL * vs[0];
    float u[4] = {t0 * vc[2], t0 * vs[2], t1 * vc[2], t1 * vs[2]};
    float z[8];
#pragma unroll
    for (int i = 0; i < 4; ++i) { z[i*2] = u[i]*vc[4]; z[i*2+1] = u[i]*vs[4]; }
#pragma unroll
    for (int i = 0; i < 8; ++i) { b[i*2] = z[i]*vc[7]; b[i*2+1] = z[i]*vs[7]; }
  }

  h2 R[16], I[16];

  // ---- G0 = D1_0(c=q0,t=q1) on real state;  B0: target q1 (op_sel swap)
  PC P0 = LOADPC(0);
  {
    h2 vq1p = hpk(vc[1], vs[1]);
    h2 mq1p = hpk(-vc[1], vs[1]);
    h2 Y0 = hpk(-P0.s0, P0.s0);
    h2 X1 = hpk(P0.sd, -P0.sd);
    h2 c0v = hsp(P0.c0), cdv = hsp(P0.cd);
#pragma unroll
    for (int s = 0; s < 16; ++s) {
      const bool Q0 = (s & 8) != 0;
      float br = b[s] * (Q0 ? P0.cA : P0.cB);
      float bi = b[s] * (Q0 ? P0.sA : P0.sB);
      h2 r = hmul(hsp(br), vq1p);
      h2 i = hmul(hsp(bi), mq1p);
      if (!Q0) {
        R[s] = hfma_sw(Y0, r, hmul(c0v, r));
        I[s] = hfma_sw(Y0, i, hmul(c0v, i));
      } else {
        R[s] = hfma_sw(cdv, r, hmul(X1, r));
        I[s] = hfma_sw(cdv, i, hmul(X1, i));
      }
    }
  }

  // ---- G1 = D3_0(c=q0,t=q1) * D1_1(c=q1,t=q2)
  PC P1 = LOADPC(1);
  {
    h2 zr1p = hpk(P1.cB, P1.cA);
    h2 zi1p[2] = { hpk(-P1.sB, -P1.sA), hpk(P1.sB, P1.sA) };
    h2 zrBp[2], ziBp[2];
#pragma unroll
    for (int t = 0; t < 2; ++t) {
      float eps = t ? 1.f : -1.f;
      float zix = eps * P1.sB, ziy = eps * P1.sA;
      float zrx = __builtin_fmaf(P0.s4, zix, P0.c4 * P1.cB);
      float zry = __builtin_fmaf(-P0.s4, ziy, P0.c4 * P1.cA);
      float zibx = __builtin_fmaf(-P0.s4, P1.cB, P0.c4 * zix);
      float ziby = __builtin_fmaf(P0.s4, P1.cA, P0.c4 * ziy);
      zrBp[t] = hpk(zrx, zry); ziBp[t] = hpk(zibx, ziby);
    }
#pragma unroll
    for (int s = 0; s < 16; ++s) {
      const int Q2 = (s >> 2) & 1;
      if (s & 8) { CDIAG(s, zrBp[Q2], ziBp[Q2]); }
      else       { CDIAG(s, zr1p, zi1p[Q2]); }
    }
  }
  // ---- B1: target q2 (register mix s<->s|4), control q1 (component vector)
  {
    h2 m00 = hpk(P1.c0, P1.sd), m01 = hpk(-P1.s0, P1.cd);
    h2 m10 = hpk(P1.s0, P1.cd), m11 = hpk(P1.c0, -P1.sd);
#pragma unroll
    for (int s = 0; s < 16; ++s) {
      if (s & 4) continue;
      const int a = s, c = s | 4;
      h2 t;
      t    = hfma(m01, R[c], hmul(m00, R[a]));
      R[c] = hfma(m11, R[c], hmul(m10, R[a])); R[a] = t;
      t    = hfma(m01, I[c], hmul(m00, I[a]));
      I[c] = hfma(m11, I[c], hmul(m10, I[a])); I[a] = t;
    }
  }

  // ---- G2 = D3_1(c=q1,t=q2) * D1_2(c=q2,t=q3)
  PC P2 = LOADPC(2);
  {
    float wr0 = P2.cB, wi0 = sgn3 * P2.sB;
    float wr1 = P2.cA, wi1 = sgn3 * P2.sA;
    h2 zrq[2] = { hpk(wr0, __builtin_fmaf(P1.s4, wi0, P1.c4*wr0)),
                  hpk(wr1, __builtin_fmaf(-P1.s4, wi1, P1.c4*wr1)) };
    h2 ziq[2] = { hpk(wi0, __builtin_fmaf(P1.c4, wi0, -P1.s4*wr0)),
                  hpk(wi1, __builtin_fmaf(P1.c4, wi1,  P1.s4*wr1)) };
#pragma unroll
    for (int s = 0; s < 16; ++s) {
      const int Q2 = (s >> 2) & 1;
      CDIAG(s, zrq[Q2], ziq[Q2]);
    }
  }
  // ---- B2: target q3 (DPP ror8), control q2 (set bit)
  {
    float Y0 = q3 ? P2.s0 : -P2.s0;
    float X1 = q3 ? -P2.sd : P2.sd;
    h2 Xv[2] = { hsp(P2.c0), hsp(X1) };
    h2 Yv[2] = { hsp(Y0), hsp(P2.cd) };
#pragma unroll
    for (int s = 0; s < 16; ++s) {
      const int Q2 = (s >> 2) & 1;
      h2 o = hdpp<0x128>(R[s]); R[s] = hfma(Yv[Q2], o, hmul(Xv[Q2], R[s]));
      o = hdpp<0x128>(I[s]);    I[s] = hfma(Yv[Q2], o, hmul(Xv[Q2], I[s]));
    }
  }

  // ---- G3 = D3_2(c=q2,t=q3) * D1_3(c=q3,t=q0)
  PC P3 = LOADPC(3);
  {
    float dr = q3 ? P3.cA : P3.cB;
    float di = q3 ? P3.sA : P3.sB;
    float ui = sgn3 * P2.s4;
    h2 z3r[2][2], z3i[2][2];  // [q2][q0]
    z3r[0][0] = hsp(dr);  z3i[0][0] = hsp(-di);
    z3r[0][1] = hsp(dr);  z3i[0][1] = hsp(di);
    z3r[1][0] = hsp(__builtin_fmaf(ui, di, P2.c4*dr));
    z3i[1][0] = hsp(__builtin_fmaf(ui, dr, -P2.c4*di));
    z3r[1][1] = hsp(__builtin_fmaf(-ui, di, P2.c4*dr));
    z3i[1][1] = hsp(__builtin_fmaf(ui, dr,  P2.c4*di));
#pragma unroll
    for (int s = 0; s < 16; ++s) {
      const int Q2 = (s >> 2) & 1, Q0 = (s >> 3) & 1;
      CDIAG(s, z3r[Q2][Q0], z3i[Q2][Q0]);
    }
  }
  // ---- B3: target q0 (register mix s<->s|8), control q3 (lane)
  {
    float m00 = q3 ? P3.sd : P3.c0, m01 = q3 ? P3.cd : -P3.s0;
    float m10 = q3 ? P3.cd : P3.s0, m11 = q3 ? -P3.sd : P3.c0;
    h2 M00 = hsp(m00), M01 = hsp(m01), M10 = hsp(m10), M11 = hsp(m11);
#pragma unroll
    for (int s = 0; s < 8; ++s) {
      const int a = s, c = s | 8;
      h2 t;
      t    = hfma(M01, R[c], hmul(M00, R[a]));
      R[c] = hfma(M11, R[c], hmul(M10, R[a])); R[a] = t;
      t    = hfma(M01, I[c], hmul(M00, I[a]));
      I[c] = hfma(M11, I[c], hmul(M10, I[a])); I[a] = t;
    }
  }

  // ---- G4 = D3_3(c=q3,t=q0) * D1_4(c=q3,t=q4)
  PC P4 = LOADPC(4);
  {
    float ar = q3 ? P3.c4 : 1.f, ai = q3 ? P3.s4 : 0.f;
    float wr = q3 ? P4.cA : P4.cB, wi = q3 ? P4.sA : P4.sB;
    float p = ar*wr, qq = ai*wi, r_ = ar*wi, t_ = ai*wr;
    h2 z4r[2][2] = {{hsp(p - qq), hsp(p + qq)}, {hsp(p + qq), hsp(p - qq)}};
    h2 z4i[2][2] = {{hsp(-r_ - t_), hsp(r_ - t_)}, {hsp(-r_ + t_), hsp(r_ + t_)}};
#pragma unroll
    for (int s = 0; s < 16; ++s) {
      const int Q0 = (s >> 3) & 1, Q4 = (s >> 1) & 1;
      CDIAG(s, z4r[Q0][Q4], z4i[Q0][Q4]);
    }
  }
  // ---- B4: target q4 (register mix s<->s|2), control q3 (lane)
  {
    float m00 = q3 ? P4.sd : P4.c0, m01 = q3 ? P4.cd : -P4.s0;
    float m10 = q3 ? P4.cd : P4.s0, m11 = q3 ? -P4.sd : P4.c0;
    h2 M00 = hsp(m00), M01 = hsp(m01), M10 = hsp(m10), M11 = hsp(m11);
#pragma unroll
    for (int s = 0; s < 16; ++s) {
      if (s & 2) continue;
      const int a = s, c = s | 2;
      h2 t;
      t    = hfma(M01, R[c], hmul(M00, R[a]));
      R[c] = hfma(M11, R[c], hmul(M10, R[a])); R[a] = t;
      t    = hfma(M01, I[c], hmul(M00, I[a]));
      I[c] = hfma(M11, I[c], hmul(M10, I[a])); I[a] = t;
    }
  }

  // ---- G5 = D3_4(c=q3,t=q4) * D1_5(c=q4,t=q5)
  PC P5 = LOADPC(5);
  {
    float ur = q3 ? P4.c4 : 1.f, ui = q3 ? P4.s4 : 0.f;
    float w0r = P5.cB, w0i = sgn5 * P5.sB;
    float w1r = P5.cA, w1i = sgn5 * P5.sA;
    h2 z5r[2] = { hsp(__builtin_fmaf(ui, w0i, ur*w0r)),
                  hsp(__builtin_fmaf(-ui, w1i, ur*w1r)) };
    h2 z5i[2] = { hsp(__builtin_fmaf(-ui, w0r, ur*w0i)),
                  hsp(__builtin_fmaf(ui, w1r, ur*w1i)) };
#pragma unroll
    for (int s = 0; s < 16; ++s) {
      const int Q4 = (s >> 1) & 1;
      CDIAG(s, z5r[Q4], z5i[Q4]);
    }
  }
  // ---- B5: target q5 (DPP quad_perm [1,0,3,2]), control q4 (set bit)
  {
    float Y0 = q5 ? P5.s0 : -P5.s0;
    float X1 = q5 ? -P5.sd : P5.sd;
    h2 Xv[2] = { hsp(P5.c0), hsp(X1) };
    h2 Yv[2] = { hsp(Y0), hsp(P5.cd) };
#pragma unroll
    for (int s = 0; s < 16; ++s) {
      const int Q4 = (s >> 1) & 1;
      h2 o = hdpp<0xB1>(R[s]); R[s] = hfma(Yv[Q4], o, hmul(Xv[Q4], R[s]));
      o = hdpp<0xB1>(I[s]);    I[s] = hfma(Yv[Q4], o, hmul(Xv[Q4], I[s]));
    }
  }

  // ---- G6 = D3_5(c=q4,t=q5) * D1_6(c=q5,t=q6)
  PC P6 = LOADPC(6);
  {
    float wr = q5 ? P6.cA : P6.cB;
    float wi = sgn6 * (q5 ? P6.sA : P6.sB);
    float vi = sgn5 * P5.s4;
    h2 z6r[2] = { hsp(wr), hsp(__builtin_fmaf(-vi, wi, P5.c4*wr)) };
    h2 z6i[2] = { hsp(wi), hsp(__builtin_fmaf(vi, wr, P5.c4*wi)) };
#pragma unroll
    for (int s = 0; s < 16; ++s) {
      const int Q4 = (s >> 1) & 1;
      CDIAG(s, z6r[Q4], z6i[Q4]);
    }
  }
  // ---- B6: target q6 (DPP quad_perm [2,3,0,1]), control q5 (lane)
  {
    float X = q5 ? (q6 ? -P6.sd : P6.sd) : P6.c0;
    float Y = q5 ? P6.cd : (q6 ? P6.s0 : -P6.s0);
    h2 Xv = hsp(X), Yv = hsp(Y);
#pragma unroll
    for (int s = 0; s < 16; ++s) {
      h2 o = hdpp<0x4E>(R[s]); R[s] = hfma(Yv, o, hmul(Xv, R[s]));
      o = hdpp<0x4E>(I[s]);    I[s] = hfma(Yv, o, hmul(Xv, I[s]));
    }
  }

  // ---- G7 = D3_6(c=q5,t=q6) * D1_7(c=q6,t=q7)
  PC P7 = LOADPC(7);
  {
    float ur = q5 ? P6.c4 : 1.f;
    float vi = sgn6 * (q5 ? P6.s4 : 0.f);
    float wr = q6 ? P7.cA : P7.cB, wi = q6 ? P7.sA : P7.sB;
    h2 z7r[2] = { hsp(__builtin_fmaf(vi, wi, ur*wr)),
                  hsp(__builtin_fmaf(-vi, wi, ur*wr)) };
    h2 z7i[2] = { hsp(__builtin_fmaf(vi, wr, -ur*wi)),
                  hsp(__builtin_fmaf(vi, wr, ur*wi)) };
#pragma unroll
    for (int s = 0; s < 16; ++s) {
      const int Q7 = s & 1;
      CDIAG(s, z7r[Q7], z7i[Q7]);
    }
  }
  // ---- B7: target q7 (register mix s<->s|1), control q6 (lane)
  {
    float m00 = q6 ? P7.sd : P7.c0, m01 = q6 ? P7.cd : -P7.s0;
    float m10 = q6 ? P7.cd : P7.s0, m11 = q6 ? -P7.sd : P7.c0;
    h2 M00 = hsp(m00), M01 = hsp(m01), M10 = hsp(m10), M11 = hsp(m11);
#pragma unroll
    for (int s = 0; s < 16; ++s) {
      if (s & 1) continue;
      const int a = s, c = s | 1;
      h2 t;
      t    = hfma(M01, R[c], hmul(M00, R[a]));
      R[c] = hfma(M11, R[c], hmul(M10, R[a])); R[a] = t;
      t    = hfma(M01, I[c], hmul(M00, I[a]));
      I[c] = hfma(M11, I[c], hmul(M10, I[a])); I[a] = t;
    }
  }

  // ---- G8 = D3_7(c=q6,t=q7) * D1_8(c=q7,t=q3)
  PC P8 = LOADPC(8);
  {
    float ur = q6 ? P7.c4 : 1.f, ui = q6 ? P7.s4 : 0.f;
    float w0r = P8.cB, w0i = sgn3 * P8.sB;
    float w1r = P8.cA, w1i = sgn3 * P8.sA;
    h2 z8r[2] = { hsp(__builtin_fmaf(ui, w0i, ur*w0r)),
                  hsp(__builtin_fmaf(-ui, w1i, ur*w1r)) };
    h2 z8i[2] = { hsp(__builtin_fmaf(-ui, w0r, ur*w0i)),
                  hsp(__builtin_fmaf(ui, w1r, ur*w1i)) };
#pragma unroll
    for (int s = 0; s < 16; ++s) {
      const int Q7 = s & 1;
      CDIAG(s, z8r[Q7], z8i[Q7]);
    }
  }
  // ---- B8: target q3 (DPP ror8), control q7 (set bit). Final D3 dropped.
  {
    float Y0 = q3 ? P8.s0 : -P8.s0;
    float X1 = q3 ? -P8.sd : P8.sd;
    h2 Xv[2] = { hsp(P8.c0), hsp(X1) };
    h2 Yv[2] = { hsp(Y0), hsp(P8.cd) };
#pragma unroll
    for (int s = 0; s < 16; ++s) {
      const int Q7 = s & 1;
      h2 o = hdpp<0x128>(R[s]); R[s] = hfma(Yv[Q7], o, hmul(Xv[Q7], R[s]));
      o = hdpp<0x128>(I[s]);    I[s] = hfma(Yv[Q7], o, hmul(Xv[Q7], I[s]));
    }
  }

  // ---- probs: marginalize q0,q2 (set bits), q1 (dot2 over halves), f32 acc
  float acc[4] = {0.f, 0.f, 0.f, 0.f};
#pragma unroll
  for (int s = 0; s < 16; ++s) {
    acc[s & 3] = hdot2(R[s], R[s], acc[s & 3]);
    acc[s & 3] = hdot2(I[s], I[s], acc[s & 3]);
  }
  // out index k = q3*16 + q4*8 + q5*4 + q6*2 + q7 ; acc[j]: j = q4*2 + q7
  const int k0 = q3 * 16 + q5 * 4 + q6 * 2;
  float* ob = out + (wv * 8 + smp) * 32 + k0;
  *(float2*)(ob) = make_float2(acc[0], acc[1]);
  *(float2*)(ob + 8) = make_float2(acc[2], acc[3]);
}

extern "C" void kernel_launch(void* const* d_in, const int* in_sizes, int n_in,
                              void* d_out, int out_size, void* d_ws, size_t ws_size,
                              hipStream_t stream) {
  const float* inputs = (const float*)d_in[0];   // (B, 8) f32
  const float* weights = (const float*)d_in[1];  // (1, 45) f32
  float* out = (float*)d_out;                    // (B, 32) f32
  const int B = in_sizes[0] / 8;

  hipLaunchKernelGGL(qnn_main, dim3(B / 32), dim3(256), 0, stream,
                     inputs, weights, out);
}